// Round 3
// baseline (168.779 us; speedup 1.0000x reference)
//
#include <hip/hip_runtime.h>
#include <hip/hip_bf16.h>

// CIN (xDeepFM) fused 3-layer kernel for MI355X — transposed-GEMM, 2 WG/CU.
// B=1024, F0=32, D=32, H=128 per layer.
// Layer: h[b,d,h] = sum_{f,g} x0[b,f,d]*S[b,g,d]*W[f*Fk+g,h] + bias[h]
//      = sum_f x0[b,f,d] * (S(b,:,d) . W_f)[h]
// Transposed MFMA: D[m=h][n=r=(b,d)] = sum_k W_f[k,h] * S[r,k]
//   A-frag = W (LDS-staged, ds_read_b128, zero VALU)
//   B-frag = S (registers, loaded once per layer, zero per-k VALU)
//   x0 scale applied post-MFMA: outacc += xs_lane * Y_f
// R3 change: one WG owns 2 batches (r = 0..63), grid 512 = 2 WGs/CU
// (2 waves/SIMD, independent barrier domains) — R2 showed MfmaUtil pinned at
// 29.5% with 1 wave/SIMD: the pipe was issue-starved, not work-bound.
// LDS 64KB: Wb[0] 32KB + Wb[1] 32KB; inter-layer state transit buffer SB
// (u32 [h/2][r], bf16-pair packed, 16KB) OVERLAYS Wb[1].

typedef __attribute__((ext_vector_type(8))) short short8;
typedef __attribute__((ext_vector_type(8))) __bf16 bf16x8;
typedef __attribute__((ext_vector_type(16))) float f32x16;
typedef __attribute__((ext_vector_type(4))) unsigned short u16x4;

#define DEVINL static __device__ __forceinline__

DEVINL unsigned short f2bf_rne(float f) {
  unsigned int u = __builtin_bit_cast(unsigned int, f);
  unsigned int r = u + 0x7fffu + ((u >> 16) & 1u);
  return (unsigned short)(r >> 16);
}

// async global->LDS, 16B per lane; LDS dest = uniform base + lane*16
DEVINL void gload_lds16(const unsigned short* g, unsigned short* l) {
  __builtin_amdgcn_global_load_lds(
      (const __attribute__((address_space(1))) unsigned int*)g,
      (__attribute__((address_space(3))) unsigned int*)l, 16, 0, 0);
}

// MFMA adapter: builtin may want v8i16 or v8bf16. SFINAE both.
template <typename V>
DEVINL auto mfma_32x32x16_bf16(V a, V b, f32x16 c, int)
    -> decltype(__builtin_amdgcn_mfma_f32_32x32x16_bf16(a, b, c, 0, 0, 0)) {
  return __builtin_amdgcn_mfma_f32_32x32x16_bf16(a, b, c, 0, 0, 0);
}
template <typename V>
DEVINL f32x16 mfma_32x32x16_bf16(V a, V b, f32x16 c, long) {
  return __builtin_amdgcn_mfma_f32_32x32x16_bf16(
      __builtin_bit_cast(bf16x8, a), __builtin_bit_cast(bf16x8, b), c, 0, 0, 0);
}
DEVINL f32x16 mfma_bf16(short8 a, short8 b, f32x16 c) {
  return mfma_32x32x16_bf16(a, b, c, 0);
}

// ---------------- W pack kernel (LDS tile transpose, coalesced both ways) --
// Packed layout per layer: [f][kb=k>>3][h][j=k&7] bf16.
__global__ void pack_w_kernel(const float* __restrict__ W0,
                              const float* __restrict__ W1,
                              const float* __restrict__ W2,
                              unsigned short* __restrict__ Wt) {
  __shared__ float tile[8][132];
  const int u = blockIdx.x;
  const float* W; int FK, f, kb, base;
  if (u < 128)      { W = W0; FK = 32;  f = u >> 2;         kb = u & 3;          base = 0; }
  else if (u < 640) { W = W1; FK = 128; f = (u - 128) >> 4; kb = (u - 128) & 15; base = 131072; }
  else              { W = W2; FK = 128; f = (u - 640) >> 4; kb = (u - 640) & 15; base = 655360; }
  const int t = threadIdx.x;
#pragma unroll
  for (int i = 0; i < 4; ++i) {
    const int e = t + i * 256;  // 0..1023
    const int kk = e >> 7, h = e & 127;
    tile[kk][h] = W[(f * FK + kb * 8 + kk) * 128 + h];
  }
  __syncthreads();
  unsigned short* dst = Wt + base + f * (FK / 8) * 1024 + kb * 1024;
  const int h = t >> 1;
  const int j0 = (t & 1) * 4;
  u16x4 v;
  v.x = f2bf_rne(tile[j0 + 0][h]);
  v.y = f2bf_rne(tile[j0 + 1][h]);
  v.z = f2bf_rne(tile[j0 + 2][h]);
  v.w = f2bf_rne(tile[j0 + 3][h]);
  *(u16x4*)&dst[t * 4] = v;
}

// ---------------- main kernel ----------------
// stage one 32KB piece (16384 u16) into LDS; wave w does chunks w*8..w*8+7
DEVINL void stage32(const unsigned short* __restrict__ src, unsigned short* dst,
                    int w, int lane) {
#pragma unroll
  for (int c = 0; c < 8; ++c) {
    const int chunk = w * 8 + c;
    gload_lds16(src + chunk * 512 + lane * 8, dst + chunk * 512);
  }
}

// FK: layer K per f (32 or 128); FPP: f's per 32KB piece; LAYER: 0,1,2
template <int FK, int FPP, int LAYER>
DEVINL void run_layer(const unsigned short* __restrict__ Wt,
                      const unsigned short* __restrict__ WtNext,
                      const float* __restrict__ bias,
                      const float* __restrict__ x0g, int wgb0,
                      float* __restrict__ outp, int outoff,
                      unsigned short (*Wb)[16384],
                      int w, int lane, int l31, int half, int mrow, int ncol) {
  constexpr int KQ = FK / 16;
  constexpr int NP = 32 / FPP;  // pieces (32 f total)
  unsigned int* SB = (unsigned int*)&Wb[1][0];

  // --- load this layer's B-frags (S) from SB into registers, once ---
  // B[k][n]: slot (half,j) holds S[r][k = kq*16 + half*8 + j], r = ncol*32+l31;
  // SB row k2 = k/2 packs (k even lo16, k odd hi16); addr = k2*64 + r
  // (bank = r%32 -> conflict-free).
  int4 sfr[KQ];
  const int r = ncol * 32 + l31;
#pragma unroll
  for (int kq = 0; kq < KQ; ++kq) {
    const int row0 = kq * 8 + half * 4;
    int4 v;
    v.x = (int)SB[(row0 + 0) * 64 + r];
    v.y = (int)SB[(row0 + 1) * 64 + r];
    v.z = (int)SB[(row0 + 2) * 64 + r];
    v.w = (int)SB[(row0 + 3) * 64 + r];
    sfr[kq] = v;
  }
  __syncthreads();  // frags consumed by all waves; piece0 arrived (vmcnt drain)

  f32x16 outacc[2];
  f32x16 zv;
#pragma unroll
  for (int e = 0; e < 16; ++e) zv[e] = 0.f;
  outacc[0] = zv; outacc[1] = zv;

  const int hW = mrow * 64 + l31;  // A-frag h (+ mt*32)
  const int xbase = (wgb0 + ncol) * 1024 + l31;  // x0[b][f][d=l31]
  float xs = x0g[xbase];  // f=0 scale

#pragma unroll 1
  for (int p = 0; p < NP; ++p) {
    if (p + 1 < NP)
      stage32(Wt + (p + 1) * 16384, &Wb[(p + 1) & 1][0], w, lane);
    const unsigned short* piece = &Wb[p & 1][0];
#pragma unroll
    for (int fi = 0; fi < FPP; ++fi) {
      const int f = p * FPP + fi;
      float xn = xs;
      if (f + 1 < 32) xn = x0g[xbase + (f + 1) * 32];  // prefetch next scale
      f32x16 Y[2];
#pragma unroll
      for (int kq = 0; kq < KQ; ++kq) {
        const int gb = fi * (KQ * 2 * 1024) + (2 * kq + half) * 1024;
        const short8 wf0 = *(const short8*)&piece[gb + (hW + 0) * 8];
        const short8 wf1 = *(const short8*)&piece[gb + (hW + 32) * 8];
        const short8 s0 = __builtin_bit_cast(short8, sfr[kq]);
        Y[0] = mfma_bf16(wf0, s0, kq == 0 ? zv : Y[0]);
        Y[1] = mfma_bf16(wf1, s0, kq == 0 ? zv : Y[1]);
      }
#pragma unroll
      for (int mt = 0; mt < 2; ++mt)
#pragma unroll
        for (int e = 0; e < 16; ++e)
          outacc[mt][e] += xs * Y[mt][e];
      xs = xn;
    }
    __syncthreads();  // piece p+1 ready; buf[p&1] free for restage
  }

  // --- epilogue ---
  // C/D layout: col = lane&31 = n (-> r); row = (reg&3)+8*(reg>>2)+4*half = h.
  float bv[2][16];
#pragma unroll
  for (int mt = 0; mt < 2; ++mt)
#pragma unroll
    for (int e = 0; e < 16; ++e)
      bv[mt][e] = bias[mrow * 64 + mt * 32 + (e & 3) + 8 * (e >> 2) + 4 * half];

  if (LAYER < 2) {
    // next state S'[r][h] = bf16(acc + bias), packed [h/2][r] u32 into SB=Wb[1]
#pragma unroll
    for (int mt = 0; mt < 2; ++mt)
#pragma unroll
      for (int g = 0; g < 4; ++g) {
        const int h2 = mrow * 32 + mt * 16 + 4 * g + 2 * half;  // hb/2
        const float v0 = outacc[mt][4 * g + 0] + bv[mt][4 * g + 0];
        const float v1 = outacc[mt][4 * g + 1] + bv[mt][4 * g + 1];
        const float v2 = outacc[mt][4 * g + 2] + bv[mt][4 * g + 2];
        const float v3 = outacc[mt][4 * g + 3] + bv[mt][4 * g + 3];
        SB[h2 * 64 + r] = (unsigned)f2bf_rne(v0) | ((unsigned)f2bf_rne(v1) << 16);
        SB[(h2 + 1) * 64 + r] =
            (unsigned)f2bf_rne(v2) | ((unsigned)f2bf_rne(v3) << 16);
      }
    // kick next layer's piece0 into Wb[0] (disjoint from SB; overlaps epilogue)
    stage32(WtNext, &Wb[0][0], w, lane);
  }

  // final output: out[b, outoff+h] = sum_d acc + 32*bias  (d-sum over l31)
#pragma unroll
  for (int mt = 0; mt < 2; ++mt) {
    float s[16];
#pragma unroll
    for (int e = 0; e < 16; ++e) {
      float v = outacc[mt][e];
      v += __shfl_xor(v, 1);
      v += __shfl_xor(v, 2);
      v += __shfl_xor(v, 4);
      v += __shfl_xor(v, 8);
      v += __shfl_xor(v, 16);
      s[e] = v + 32.0f * bv[mt][e];
    }
    if (l31 == 0) {
#pragma unroll
      for (int g = 0; g < 4; ++g) {
        const int h = mrow * 64 + mt * 32 + 8 * g + 4 * half;
        float4 o = {s[4 * g + 0], s[4 * g + 1], s[4 * g + 2], s[4 * g + 3]};
        *(float4*)&outp[ncol * 384 + outoff + h] = o;
      }
    }
  }

  if (LAYER < 2) __syncthreads();  // S' visible before next layer's frag load
}

__global__ __launch_bounds__(256, 2) void cin_kernel(
    const float* __restrict__ x0g, const unsigned short* __restrict__ Wt,
    const float* __restrict__ b0, const float* __restrict__ b1,
    const float* __restrict__ b2, float* __restrict__ out) {
  __shared__ __align__(16) unsigned short Wb[2][16384];  // 64KB total

  const int t = threadIdx.x;
  const int lane = t & 63;
  const int w = t >> 6;
  const int mrow = w >> 1;  // m(h)-tile of 64
  const int ncol = w & 1;   // n(r)-tile of 32 (one batch per wave)
  const int l31 = lane & 31, half = lane >> 5;
  const int wgb0 = blockIdx.x * 2;  // 2 batches per WG

  // prologue: kick L0 piece0 -> Wb[0]; pack S1 = bf16(x0) into SB=Wb[1]
  stage32(Wt, &Wb[0][0], w, lane);
  unsigned int* SB = (unsigned int*)&Wb[1][0];
#pragma unroll
  for (int s = 0; s < 4; ++s) {
    const int i = t + s * 256;  // 0..1023
    const int r = i & 63, g2 = i >> 6;
    const float* p = &x0g[(wgb0 + (r >> 5)) * 1024 + (2 * g2) * 32 + (r & 31)];
    SB[g2 * 64 + r] =
        (unsigned)f2bf_rne(p[0]) | ((unsigned)f2bf_rne(p[32]) << 16);
  }
  __syncthreads();  // S1 visible

  float* outp = out + (size_t)wgb0 * 384;

  run_layer<32, 4, 0>(Wt, Wt + 131072, b0, x0g, wgb0, outp, 0, Wb,
                      w, lane, l31, half, mrow, ncol);
  run_layer<128, 1, 1>(Wt + 131072, Wt + 655360, b1, x0g, wgb0, outp, 128, Wb,
                       w, lane, l31, half, mrow, ncol);
  run_layer<128, 1, 2>(Wt + 655360, (const unsigned short*)nullptr, b2, x0g,
                       wgb0, outp, 256, Wb, w, lane, l31, half, mrow, ncol);
}

extern "C" void kernel_launch(void* const* d_in, const int* in_sizes, int n_in,
                              void* d_out, int out_size, void* d_ws, size_t ws_size,
                              hipStream_t stream) {
  (void)in_sizes; (void)n_in; (void)out_size; (void)ws_size;
  const float* x0 = (const float*)d_in[0];
  const float* W0 = (const float*)d_in[1];
  const float* W1 = (const float*)d_in[2];
  const float* W2 = (const float*)d_in[3];
  const float* b0 = (const float*)d_in[4];
  const float* b1 = (const float*)d_in[5];
  const float* b2 = (const float*)d_in[6];
  unsigned short* Wt = (unsigned short*)d_ws;  // 2,359,296 B

  pack_w_kernel<<<1152, 256, 0, stream>>>(W0, W1, W2, Wt);
  // 512 WGs x 256 thr = 2 WGs/CU (2 waves/SIMD) — independent barrier domains
  cin_kernel<<<512, 256, 0, stream>>>(x0, Wt, b0, b1, b2, (float*)d_out);
}